// Round 4
// baseline (744.289 us; speedup 1.0000x reference)
//
#include <hip/hip_runtime.h>

// ---- problem constants ----
#define BATCH 16
#define RB    8
#define CITIES 1023
#define NODES 1024
#define HDIM  64
#define H2DIM 128
#define KTOT  3072          // 3 poly terms * 1024 (c padded to 1024)

// sigmoid(x) ~= 0.5 + C1*x + C3*x^3 on [-1,1], max err ~1.3e-4
#define C1f 0.24944119f
#define C3f (-0.01850586f)

typedef __bf16    bf16x8 __attribute__((ext_vector_type(8)));
typedef _Float16  f16x8  __attribute__((ext_vector_type(8)));
typedef _Float16  f16x2  __attribute__((ext_vector_type(2)));
typedef float     f32x4  __attribute__((ext_vector_type(4)));

__device__ __forceinline__ f32x4 mfma16(bf16x8 a, bf16x8 b, f32x4 c){
    return __builtin_amdgcn_mfma_f32_16x16x32_bf16(a, b, c, 0, 0, 0);
}
__device__ __forceinline__ f32x4 mfma16h(f16x8 a, f16x8 b, f32x4 c){
    return __builtin_amdgcn_mfma_f32_16x16x32_f16(a, b, c, 0, 0, 0);
}
__device__ __forceinline__ unsigned short f2b(float f){
    __bf16 b = (__bf16)f;
    return __builtin_bit_cast(unsigned short, b);
}
__device__ __forceinline__ float b2f(unsigned short u){
    unsigned int t = ((unsigned int)u) << 16;
    return __builtin_bit_cast(float, t);
}
__device__ __forceinline__ unsigned short f2h(float f){
    _Float16 h = (_Float16)f;
    return __builtin_bit_cast(unsigned short, h);
}
__device__ __forceinline__ float h2f(unsigned short u){
    return (float)__builtin_bit_cast(_Float16, u);
}
__device__ __forceinline__ void async16(const void* g, void* l){
    __builtin_amdgcn_global_load_lds(
        (const __attribute__((address_space(1))) unsigned int*)g,
        (__attribute__((address_space(3))) unsigned int*)l, 16, 0, 0);
}
template<int N>
__device__ __forceinline__ void wait_vmcnt(){
    asm volatile("s_waitcnt vmcnt(%0)" :: "i"(N) : "memory");
}

// ---------------- kernel: x_a[b,n] = max_r x_a_state*(assign_prev+action) ----------------
__global__ __launch_bounds__(256) void xa_k(const float* __restrict__ xs,
        const float* __restrict__ ap, const float* __restrict__ act,
        float* __restrict__ xa){
    int idx = blockIdx.x*256 + threadIdx.x;       // 16384
    int b = idx >> 10, n = idx & 1023;
    float m = -1e30f;
    #pragma unroll
    for(int r=0;r<RB;r++){
        size_t o = (((size_t)b*RB + r)<<10) + n;
        m = fmaxf(m, xs[o]*(ap[o]+act[o]));
    }
    xa[idx] = m;
}

// ---------------- presence MLP + softmax; 128 thr, 8 pts/thread in registers -------------
__global__ __launch_bounds__(128) void presence_k(const float* __restrict__ edge,
        const float* __restrict__ W1, const float* __restrict__ W2,
        const float* __restrict__ avail,
        unsigned short* __restrict__ P, unsigned short* __restrict__ D){
    int c = blockIdx.x, b = blockIdx.y;
    int tid = threadIdx.x;
    __shared__ f16x8 Wpk[32];    // per h-pair: {wx0,wx1, wy0,wy1, wz0,wz1, w2_0,w2_1}
    __shared__ float red[2];
    if(tid < 32){
        int h0 = tid*2;
        f16x8 w;
        w[0]=(_Float16)W1[h0];       w[1]=(_Float16)W1[h0+1];
        w[2]=(_Float16)W1[64+h0];    w[3]=(_Float16)W1[64+h0+1];
        w[4]=(_Float16)W1[128+h0];   w[5]=(_Float16)W1[128+h0+1];
        w[6]=(_Float16)W2[h0];       w[7]=(_Float16)W2[h0+1];
        Wpk[tid] = w;
    }
    __syncthreads();
    f16x2 e0d[8], e1d[8], e2d[8];
    float acc[8];
    size_t ebase = (((size_t)b*CITIES + c)<<10)*3;
    #pragma unroll
    for(int j=0;j<8;j++){
        int n = tid + j*128;
        size_t ea = ebase + (size_t)n*3;
        _Float16 v0=(_Float16)edge[ea], v1=(_Float16)edge[ea+1], v2=(_Float16)edge[ea+2];
        e0d[j]=(f16x2){v0,v0}; e1d[j]=(f16x2){v1,v1}; e2d[j]=(f16x2){v2,v2};
        acc[j]=0.f;
    }
    const f16x2 z2 = {(_Float16)0, (_Float16)0};
    for(int hp=0;hp<32;hp++){
        f16x8 w = Wpk[hp];
        f16x2 wx={w[0],w[1]}, wy={w[2],w[3]}, wz={w[4],w[5]}, w2={w[6],w[7]};
        #pragma unroll
        for(int j=0;j<8;j++){
            f16x2 a = e0d[j]*wx + e1d[j]*wy + e2d[j]*wz;
            a = __builtin_elementwise_max(a, z2);
            acc[j] = __builtin_amdgcn_fdot2(a, w2, acc[j], false);
        }
    }
    float lg[8], ex[8];
    #pragma unroll
    for(int j=0;j<8;j++){
        int n = tid + j*128;
        float h2 = fmaxf(acc[j], 0.f);             // relu; /TAU with TAU=1
        float mk = (n==c) ? 0.f : avail[(b<<10)+n];
        lg[j] = h2*mk - (1.f-mk)*1e10f;
    }
    int wv = tid>>6, ln = tid&63;
    float mx = -1e30f;
    #pragma unroll
    for(int j=0;j<8;j++) mx = fmaxf(mx, lg[j]);
    for(int o=32;o>0;o>>=1) mx = fmaxf(mx, __shfl_xor(mx,o,64));
    if(ln==0) red[wv]=mx;
    __syncthreads();
    mx = fmaxf(red[0],red[1]);
    __syncthreads();
    float s = 0.f;
    #pragma unroll
    for(int j=0;j<8;j++){ ex[j] = expf(lg[j]-mx); s += ex[j]; }
    for(int o=32;o>0;o>>=1) s += __shfl_xor(s,o,64);
    if(ln==0) red[wv]=s;
    __syncthreads();
    s = red[0]+red[1];
    float inv = 1.f/s;
    size_t pbase = ((size_t)b*CITIES + c)<<10;
    #pragma unroll
    for(int j=0;j<8;j++){
        int n = tid + j*128;
        P[pbase+n] = f2h(ex[j]*inv);
        D[pbase+n] = __builtin_bit_cast(unsigned short, e0d[j][0]);
    }
}

// ------- build A' [b][i][3*1024] fp16 = {p, p*d, p*d^3} transposed -----------------------
__global__ __launch_bounds__(256) void abuild_k(const unsigned short* __restrict__ P,
        const unsigned short* __restrict__ D, unsigned short* __restrict__ A){
    int ct = blockIdx.x, nt = blockIdx.y, b = blockIdx.z;
    int tid = threadIdx.x;
    __shared__ unsigned short Pt[32][36];
    __shared__ unsigned short Dt[32][36];
    {
        int crow = tid>>3, ng = (tid&7)<<2;
        int c = ct*32 + crow;
        if(c < CITIES){
            size_t o = (((size_t)b*CITIES + c)<<10) + nt*32 + ng;
            *(ushort4*)&Pt[crow][ng] = *(const ushort4*)&P[o];
            *(ushort4*)&Dt[crow][ng] = *(const ushort4*)&D[o];
        } else {
            ushort4 z; z.x=0;z.y=0;z.z=0;z.w=0;
            *(ushort4*)&Pt[crow][ng] = z;
            *(ushort4*)&Dt[crow][ng] = z;
        }
    }
    __syncthreads();
    int nrow = tid>>3, cg = (tid&7)<<2;
    ushort4 w0, w1, w2;
    #pragma unroll
    for(int j=0;j<4;j++){
        float p = h2f(Pt[cg+j][nrow]);
        float d = h2f(Dt[cg+j][nrow]);
        float d3 = d*d*d;
        ((unsigned short*)&w0)[j] = f2h(p);
        ((unsigned short*)&w1)[j] = f2h(p*d);
        ((unsigned short*)&w2)[j] = f2h(p*d3);
    }
    size_t abase = ((size_t)(b<<10) + nt*32 + nrow)*KTOT + ct*32 + cg;
    *(ushort4*)&A[abase]      = w0;
    *(ushort4*)&A[abase+1024] = w1;
    *(ushort4*)&A[abase+2048] = w2;
}

// ---------------- initial B'^T [b][h][kc] = q_k(h) * U0[b][c][h] (fp16) ------------------
__global__ __launch_bounds__(256) void binit_k(const float* __restrict__ U0,
        const float* __restrict__ We, unsigned short* __restrict__ BT, int nout){
    int kc = blockIdx.x*256 + threadIdx.x;   // 0..3071
    int h = blockIdx.y, b = blockIdx.z;
    int k = kc >> 10, c = kc & 1023;
    float we = We[h];
    float q = (k==0) ? 0.5f : (k==1 ? C1f*we : C3f*we*we*we);
    float u = (c < CITIES) ? U0[(((size_t)b<<10) + c)*nout + h] : 0.f;
    BT[((size_t)(b*nout + h))*KTOT + kc] = f2h(q*u);
}

#define SR 72

// ======== fused T1: full-K GEMM (M=32, N=64, K=3072) + reduce1 epilogue ==================
// grid (32 mt, 16 b) = 512 blocks, 256 thr, 2 blocks/CU (LDS 36 KB) -> 2 waves/SIMD from
// INDEPENDENT blocks: block B computes while block A waits at its barrier.
// Waves: (wm,wn) 2x2; wave owns 16 rows x 32 cols. 3-buffer ring, counted vmcnt(3).
template<bool LAST>
__global__ __launch_bounds__(256) void fused1_k(const unsigned short* __restrict__ Ap,
        const unsigned short* __restrict__ BT,
        const float* __restrict__ Wl1a, const float* __restrict__ Wl1b,
        const float* __restrict__ Wx1a, const float* __restrict__ Wx1b,
        const float* __restrict__ We1a, const float* __restrict__ xa,
        unsigned short* __restrict__ Bnext, float* __restrict__ ua, float* __restrict__ ub){
    int mt = blockIdx.x, b = blockIdx.y;
    int i0 = mt*32;
    int tid = threadIdx.x, wave=tid>>6, lane=tid&63, quad=lane>>4, l16=lane&15;
    int wm = wave>>1, wn = wave&1;
    // ring: 3 x 12288 B (A 4K + B 8K); epilogue aliases first 27648 B
    __shared__ __align__(16) char smem[36864];
    unsigned short* Lh = (unsigned short*)smem;             // 32*SR*2 = 4608
    unsigned short* Ll = (unsigned short*)(smem + 4608);
    unsigned short* Wh = (unsigned short*)(smem + 9216);    // 64*SR*2 = 9216
    unsigned short* Wo = (unsigned short*)(smem + 18432);

    f32x4 zero = {0.f,0.f,0.f,0.f};
    f32x4 gacc[2] = {zero,zero};
    const unsigned short* pa;
    const unsigned short* pb[2];
    {
        int r = tid>>3, ch = tid&7;
        pa = Ap + ((size_t)(b<<10) + i0 + r)*KTOT + ((ch ^ (r&7))<<3);
    }
    #pragma unroll
    for(int rd=0; rd<2; rd++){
        int idx = rd*256 + tid, r = idx>>3, ch = idx&7;
        pb[rd] = BT + ((size_t)b*64 + r)*KTOT + ((ch ^ (r&7))<<3);
    }
    int sw = l16&7;
    auto stage = [&](char* buf){
        unsigned short* At = (unsigned short*)buf;
        unsigned short* Bt = At + 2048;
        async16(pa, At + tid*8); pa += 64;
        #pragma unroll
        for(int rd=0; rd<2; rd++){ async16(pb[rd], Bt + rd*2048 + tid*8); pb[rd] += 64; }
    };
    auto comp = [&](const char* buf){
        const unsigned short* At = (const unsigned short*)buf;
        const unsigned short* Bt = At + 2048;
        #pragma unroll
        for(int kb=0; kb<2; kb++){
            f16x8 af = *(const f16x8*)&At[(wm*16 + l16)*64 + (((kb*4+quad)^sw)<<3)];
            #pragma unroll
            for(int nt2=0; nt2<2; nt2++){
                f16x8 bf = *(const f16x8*)&Bt[(wn*32 + nt2*16 + l16)*64 + (((kb*4+quad)^sw)<<3)];
                gacc[nt2] = mfma16h(af, bf, gacc[nt2]);
            }
        }
    };
    char* b0 = smem; char* b1 = smem + 12288; char* b2 = smem + 24576;
    stage(b0); stage(b1);                       // 6 loads/thread in flight
    wait_vmcnt<3>(); __builtin_amdgcn_s_barrier();
    for(int kk=0; kk<46; kk++){
        stage(b2);
        comp(b0);
        wait_vmcnt<3>(); __builtin_amdgcn_s_barrier();
        char* tp=b0; b0=b1; b1=b2; b2=tp;
    }
    comp(b0);
    wait_vmcnt<0>(); __builtin_amdgcn_s_barrier();
    comp(b1);
    __syncthreads();
    // ---- epilogue: write l (hi/lo bf16) to LDS, load W_l, small MFMA, relu, emit ----
    #pragma unroll
    for(int nt2=0; nt2<2; nt2++){
        int h = wn*32 + nt2*16 + l16;
        #pragma unroll
        for(int rr=0; rr<4; rr++){
            int i = wm*16 + quad*4 + rr;
            float v = gacc[nt2][rr];
            unsigned short hh = f2b(v);
            Lh[i*SR + h] = hh;
            Ll[i*SR + h] = f2b(v - b2f(hh));
        }
    }
    {
        int k = tid>>2, n0 = (tid&3)*16;
        for(int j=0;j<16;j++){
            float w = Wl1a[k*64 + n0 + j];
            unsigned short hh = f2b(w);
            Wh[(n0+j)*SR + k] = hh;
            Wo[(n0+j)*SR + k] = f2b(w - b2f(hh));
        }
    }
    __syncthreads();
    f32x4 acc[2] = {zero,zero};
    #pragma unroll
    for(int kc=0;kc<2;kc++){
        bf16x8 ah = *(const bf16x8*)&Lh[(wm*16+l16)*SR + kc*32 + quad*8];
        bf16x8 al = *(const bf16x8*)&Ll[(wm*16+l16)*SR + kc*32 + quad*8];
        #pragma unroll
        for(int nt2=0;nt2<2;nt2++){
            bf16x8 bh = *(const bf16x8*)&Wh[(wn*32+nt2*16+l16)*SR + kc*32 + quad*8];
            bf16x8 bl = *(const bf16x8*)&Wo[(wn*32+nt2*16+l16)*SR + kc*32 + quad*8];
            acc[nt2] = mfma16(ah, bh, acc[nt2]);
            acc[nt2] = mfma16(ah, bl, acc[nt2]);
            acc[nt2] = mfma16(al, bh, acc[nt2]);
        }
    }
    int gi = i0 + wm*16 + quad*4;
    float4 xav = *(const float4*)&xa[(b<<10) + gi];
    float xr[4] = {xav.x, xav.y, xav.z, xav.w};
    if(!LAST){
        #pragma unroll
        for(int nt2=0;nt2<2;nt2++){
            int h = wn*32 + nt2*16 + l16;
            float wx = Wx1a[h];
            float we = We1a[h];
            float q1 = C1f*we, q2 = C3f*we*we*we;
            ushort4 w0,w1,w2;
            #pragma unroll
            for(int rr=0;rr<4;rr++){
                float u = fmaxf(acc[nt2][rr] + xr[rr]*wx, 0.f);
                bool pad = (gi+rr == 1023);
                ((unsigned short*)&w0)[rr] = pad?(unsigned short)0:f2h(0.5f*u);
                ((unsigned short*)&w1)[rr] = pad?(unsigned short)0:f2h(q1*u);
                ((unsigned short*)&w2)[rr] = pad?(unsigned short)0:f2h(q2*u);
            }
            size_t base = ((size_t)(b*64 + h))*KTOT + gi;
            *(ushort4*)&Bnext[base]      = w0;
            *(ushort4*)&Bnext[base+1024] = w1;
            *(ushort4*)&Bnext[base+2048] = w2;
        }
    } else {
        #pragma unroll
        for(int nt2=0;nt2<2;nt2++){
            int h = wn*32 + nt2*16 + l16; float wx = Wx1a[h];
            #pragma unroll
            for(int rr=0;rr<4;rr++)
                ua[(((size_t)b<<10)+gi+rr)*64 + h] = fmaxf(acc[nt2][rr] + xr[rr]*wx, 0.f);
        }
        __syncthreads();
        { int k = tid>>2, n0 = (tid&3)*16;
          for(int j=0;j<16;j++){
              float w = Wl1b[k*64 + n0 + j];
              unsigned short hh = f2b(w);
              Wh[(n0+j)*SR + k] = hh;
              Wo[(n0+j)*SR + k] = f2b(w - b2f(hh));
          } }
        __syncthreads();
        f32x4 acc2[2] = {zero,zero};
        #pragma unroll
        for(int kc=0;kc<2;kc++){
            bf16x8 ah = *(const bf16x8*)&Lh[(wm*16+l16)*SR + kc*32 + quad*8];
            bf16x8 al = *(const bf16x8*)&Ll[(wm*16+l16)*SR + kc*32 + quad*8];
            #pragma unroll
            for(int nt2=0;nt2<2;nt2++){
                bf16x8 bh = *(const bf16x8*)&Wh[(wn*32+nt2*16+l16)*SR + kc*32 + quad*8];
                bf16x8 bl = *(const bf16x8*)&Wo[(wn*32+nt2*16+l16)*SR + kc*32 + quad*8];
                acc2[nt2] = mfma16(ah, bh, acc2[nt2]);
                acc2[nt2] = mfma16(ah, bl, acc2[nt2]);
                acc2[nt2] = mfma16(al, bh, acc2[nt2]);
            }
        }
        #pragma unroll
        for(int nt2=0;nt2<2;nt2++){
            int h = wn*32 + nt2*16 + l16; float wx = Wx1b[h];
            #pragma unroll
            for(int rr=0;rr<4;rr++)
                ub[(((size_t)b<<10)+gi+rr)*64 + h] = fmaxf(acc2[nt2][rr] + xr[rr]*wx, 0.f);
        }
    }
}

// ---------------- x2 = concat(ua,ub) @ W_x_2  (hi/lo MFMA, 2 K-phases) -------------------
__global__ __launch_bounds__(256) void x2_k(const float* __restrict__ ua,
        const float* __restrict__ ub, const float* __restrict__ Wx2,
        float* __restrict__ x2){
    int mt = blockIdx.x, b = blockIdx.y;
    int i0 = mt*64;
    int tid = threadIdx.x, wave=tid>>6, lane=tid&63, quad=lane>>4, l16=lane&15;
    __shared__ __align__(16) unsigned short Uh[64*SR], Ul[64*SR];
    __shared__ __align__(16) unsigned short Wh[128*SR], Wo[128*SR];
    f32x4 zero = {0.f,0.f,0.f,0.f};
    f32x4 acc[8];
    #pragma unroll
    for(int nt=0;nt<8;nt++) acc[nt]=zero;
    for(int ph=0; ph<2; ph++){
        if(ph) __syncthreads();
        {
            int k = tid>>2, n0 = (tid&3)*32;
            for(int j=0;j<32;j++){
                float w = Wx2[(ph*64 + k)*128 + n0 + j];
                unsigned short hh = f2b(w);
                Wh[(n0+j)*SR + k] = hh;
                Wo[(n0+j)*SR + k] = f2b(w - b2f(hh));
            }
            int i = tid>>2, c0 = (tid&3)*16;
            const float* src = (ph ? ub : ua) + (((size_t)b<<10)+i0+i)*64 + c0;
            #pragma unroll
            for(int j=0;j<4;j++){
                float4 v = *(const float4*)(src + j*4);
                float vv[4] = {v.x, v.y, v.z, v.w};
                #pragma unroll
                for(int t=0;t<4;t++){
                    unsigned short hh = f2b(vv[t]);
                    Uh[i*SR + c0 + j*4 + t] = hh;
                    Ul[i*SR + c0 + j*4 + t] = f2b(vv[t] - b2f(hh));
                }
            }
        }
        __syncthreads();
        #pragma unroll
        for(int kc=0;kc<2;kc++){
            bf16x8 ah = *(const bf16x8*)&Uh[(wave*16+l16)*SR + kc*32 + quad*8];
            bf16x8 al = *(const bf16x8*)&Ul[(wave*16+l16)*SR + kc*32 + quad*8];
            #pragma unroll
            for(int nt=0;nt<8;nt++){
                bf16x8 bh = *(const bf16x8*)&Wh[(nt*16+l16)*SR + kc*32 + quad*8];
                bf16x8 bl = *(const bf16x8*)&Wo[(nt*16+l16)*SR + kc*32 + quad*8];
                acc[nt] = mfma16(ah, bh, acc[nt]);
                acc[nt] = mfma16(ah, bl, acc[nt]);
                acc[nt] = mfma16(al, bh, acc[nt]);
            }
        }
    }
    int gi = i0 + wave*16 + quad*4;
    #pragma unroll
    for(int nt=0;nt<8;nt++){
        int h = nt*16 + l16;
        #pragma unroll
        for(int rr=0;rr<4;rr++)
            x2[(((size_t)b<<10)+gi+rr)*128 + h] = acc[nt][rr];
    }
}

// ======== fused T2: full-K GEMM (M=32, N=128, K=3072) + reduce2 epilogue =================
// grid (32,16) = 512 blocks, 2 blocks/CU (LDS 60 KB, static). Waves 2x2: 16 rows x 64 cols.
// 3-buffer ring (3 x 20480 B), counted vmcnt(5).
template<bool LAST>
__global__ __launch_bounds__(256) void fused2_k(const unsigned short* __restrict__ Ap,
        const unsigned short* __restrict__ BT,
        const float* __restrict__ Wl2, const float* __restrict__ x2,
        const float* __restrict__ We2, const float* __restrict__ WQ,
        unsigned short* __restrict__ Bnext, float* __restrict__ out){
    int mt = blockIdx.x, b = blockIdx.y;
    int i0 = mt*32;
    int tid = threadIdx.x, wave=tid>>6, lane=tid&63, quad=lane>>4, l16=lane&15;
    int wm = wave>>1, wn = wave&1;
    __shared__ __align__(16) char smem[61440];
    __shared__ float red[4];
    unsigned short* Lh = (unsigned short*)smem;             // 32*SR*2 = 4608
    unsigned short* Ll = (unsigned short*)(smem + 4608);
    unsigned short* Wh = (unsigned short*)(smem + 9216);    // 128*SR*2 = 18432
    unsigned short* Wo = (unsigned short*)(smem + 27648);   // ends 46080

    f32x4 zero = {0.f,0.f,0.f,0.f};
    f32x4 gacc[4] = {zero,zero,zero,zero};
    const unsigned short* pa;
    const unsigned short* pb[4];
    {
        int r = tid>>3, ch = tid&7;
        pa = Ap + ((size_t)(b<<10) + i0 + r)*KTOT + ((ch ^ (r&7))<<3);
    }
    #pragma unroll
    for(int rd=0; rd<4; rd++){
        int idx = rd*256 + tid, r = idx>>3, ch = idx&7;
        pb[rd] = BT + ((size_t)b*128 + r)*KTOT + ((ch ^ (r&7))<<3);
    }
    int sw = l16&7;
    auto stage = [&](char* buf){
        unsigned short* At = (unsigned short*)buf;
        unsigned short* Bt = At + 2048;
        async16(pa, At + tid*8); pa += 64;
        #pragma unroll
        for(int rd=0; rd<4; rd++){ async16(pb[rd], Bt + rd*2048 + tid*8); pb[rd] += 64; }
    };
    auto comp = [&](const char* buf){
        const unsigned short* At = (const unsigned short*)buf;
        const unsigned short* Bt = At + 2048;
        #pragma unroll
        for(int kb=0; kb<2; kb++){
            f16x8 af = *(const f16x8*)&At[(wm*16 + l16)*64 + (((kb*4+quad)^sw)<<3)];
            #pragma unroll
            for(int nt=0; nt<4; nt++){
                f16x8 bf = *(const f16x8*)&Bt[(wn*64 + nt*16 + l16)*64 + (((kb*4+quad)^sw)<<3)];
                gacc[nt] = mfma16h(af, bf, gacc[nt]);
            }
        }
    };
    char* b0 = smem; char* b1 = smem + 20480; char* b2 = smem + 40960;
    stage(b0); stage(b1);                       // 10 loads/thread in flight
    wait_vmcnt<5>(); __builtin_amdgcn_s_barrier();
    for(int kk=0; kk<46; kk++){
        stage(b2);
        comp(b0);
        wait_vmcnt<5>(); __builtin_amdgcn_s_barrier();
        char* tp=b0; b0=b1; b1=b2; b2=tp;
    }
    comp(b0);
    wait_vmcnt<0>(); __builtin_amdgcn_s_barrier();
    comp(b1);
    __syncthreads();
    // ---- epilogue: 2 phases over k-halves; waves with wn==ph own that l-half ----
    f32x4 fac[4] = {zero,zero,zero,zero};
    #pragma unroll
    for(int ph=0; ph<2; ph++){
        if(ph) __syncthreads();
        if(wn == ph){
            #pragma unroll
            for(int nt=0; nt<4; nt++){
                int hh_col = nt*16 + l16;
                #pragma unroll
                for(int rr=0; rr<4; rr++){
                    int i = wm*16 + quad*4 + rr;
                    float v = gacc[nt][rr];
                    unsigned short hh = f2b(v);
                    Lh[i*SR + hh_col] = hh;
                    Ll[i*SR + hh_col] = f2b(v - b2f(hh));
                }
            }
        }
        {
            int k = tid>>2, n0 = (tid&3)*32;
            for(int j=0;j<32;j++){
                float w = Wl2[(ph*64 + k)*128 + n0 + j];
                unsigned short hh = f2b(w);
                Wh[(n0+j)*SR + k] = hh;
                Wo[(n0+j)*SR + k] = f2b(w - b2f(hh));
            }
        }
        __syncthreads();
        #pragma unroll
        for(int kc=0;kc<2;kc++){
            bf16x8 ah = *(const bf16x8*)&Lh[(wm*16+l16)*SR + kc*32 + quad*8];
            bf16x8 al = *(const bf16x8*)&Ll[(wm*16+l16)*SR + kc*32 + quad*8];
            #pragma unroll
            for(int nt=0;nt<4;nt++){
                bf16x8 bh = *(const bf16x8*)&Wh[(wn*64+nt*16+l16)*SR + kc*32 + quad*8];
                bf16x8 bl = *(const bf16x8*)&Wo[(wn*64+nt*16+l16)*SR + kc*32 + quad*8];
                fac[nt] = mfma16(ah, bh, fac[nt]);
                fac[nt] = mfma16(ah, bl, fac[nt]);
                fac[nt] = mfma16(al, bh, fac[nt]);
            }
        }
    }
    int gi = i0 + wm*16 + quad*4;
    float qp = 0.f;
    #pragma unroll
    for(int nt=0;nt<4;nt++){
        int h = wn*64 + nt*16 + l16;
        float g[4];
        #pragma unroll
        for(int rr=0;rr<4;rr++)
            g[rr] = fmaxf(fac[nt][rr] + x2[(((size_t)b<<10)+gi+rr)*128 + h], 0.f);
        if(!LAST){
            float we = We2[h];
            float q1 = C1f*we, q2 = C3f*we*we*we;
            ushort4 w0,w1,w2;
            #pragma unroll
            for(int rr=0;rr<4;rr++){
                bool pad = (gi+rr == 1023);
                ((unsigned short*)&w0)[rr] = pad?(unsigned short)0:f2h(0.5f*g[rr]);
                ((unsigned short*)&w1)[rr] = pad?(unsigned short)0:f2h(q1*g[rr]);
                ((unsigned short*)&w2)[rr] = pad?(unsigned short)0:f2h(q2*g[rr]);
            }
            size_t base = ((size_t)(b*128 + h))*KTOT + gi;
            *(ushort4*)&Bnext[base]      = w0;
            *(ushort4*)&Bnext[base+1024] = w1;
            *(ushort4*)&Bnext[base+2048] = w2;
        } else {
            float wq = WQ[h];
            #pragma unroll
            for(int rr=0;rr<4;rr++) qp = fmaf(g[rr], wq, qp);
        }
    }
    if(LAST){
        for(int o=32;o>0;o>>=1) qp += __shfl_xor(qp,o,64);
        if(lane==0) red[wave]=qp;
        __syncthreads();
        if(tid==0) atomicAdd(&out[b], red[0]+red[1]+red[2]+red[3]);
    }
}

// ---------------- host launch ------------------------------------------------------------
extern "C" void kernel_launch(void* const* d_in, const int* in_sizes, int n_in,
                              void* d_out, int out_size, void* d_ws, size_t ws_size,
                              hipStream_t stream){
    (void)in_sizes; (void)n_in; (void)out_size; (void)ws_size;
    const float* xs   = (const float*)d_in[0];
    const float* ap   = (const float*)d_in[1];
    const float* act  = (const float*)d_in[2];
    const float* edge = (const float*)d_in[3];
    const float* avail= (const float*)d_in[4];
    const float* ua0  = (const float*)d_in[5];
    const float* g0   = (const float*)d_in[7];
    const float* W1p  = (const float*)d_in[8];
    const float* W2p  = (const float*)d_in[9];
    const float* Wx1a = (const float*)d_in[10];
    const float* We1a = (const float*)d_in[11];
    const float* Wl1a = (const float*)d_in[12];
    const float* Wx1b = (const float*)d_in[13];
    const float* Wl1b = (const float*)d_in[15];
    const float* Wx2  = (const float*)d_in[16];
    const float* We2  = (const float*)d_in[17];
    const float* Wl2  = (const float*)d_in[18];
    const float* WQ   = (const float*)d_in[19];
    float* out = (float*)d_out;

    char* ws = (char*)d_ws;
    // A' (persistent): 16*1024*3072*2 = 100,663,296 B
    unsigned short* Abuf = (unsigned short*)ws;
    char* r2 = ws + 100663296;
    // P/D (fp16) live only until abuild; aliased with B' buffers after:
    unsigned short* Pbuf = (unsigned short*)r2;                      // 33,521,664
    unsigned short* Dbuf = (unsigned short*)(r2 + 33521664);         // 33,521,664 (ends 67,043,328)
    unsigned short* BT1a = (unsigned short*)r2;                      //  6,291,456
    unsigned short* BT1b = (unsigned short*)(r2 + 6291456);          //  6,291,456
    unsigned short* BT2a = (unsigned short*)(r2 + 12582912);         // 12,582,912
    unsigned short* BT2b = (unsigned short*)(r2 + 25165824);         // 12,582,912 (ends 37,748,736)
    float* uaB           = (float*)(r2 + 117440512);                 //  4,194,304
    float* ubB           = (float*)(r2 + 121634816);                 //  4,194,304
    float* x2B           = (float*)(r2 + 125829120);                 //  8,388,608
    float* xaB           = (float*)(r2 + 134217728);                 //     65,536
    unsigned short* BT1[2] = {BT1a, BT1b};
    unsigned short* BT2[2] = {BT2a, BT2b};

    hipMemsetAsync(d_out, 0, BATCH*sizeof(float), stream);
    xa_k<<<64,256,0,stream>>>(xs, ap, act, xaB);
    presence_k<<<dim3(CITIES,BATCH),128,0,stream>>>(edge, W1p, W2p, avail, Pbuf, Dbuf);
    abuild_k<<<dim3(32,32,BATCH),256,0,stream>>>(Pbuf, Dbuf, Abuf);
    binit_k<<<dim3(12,64,BATCH),256,0,stream>>>(ua0, We1a, BT1[0], 64);
    for(int it=0; it<5; it++){
        if(it<4)
            fused1_k<false><<<dim3(32,16),256,0,stream>>>(Abuf, BT1[it&1], Wl1a, Wl1b,
                Wx1a, Wx1b, We1a, xaB, BT1[(it+1)&1], uaB, ubB);
        else
            fused1_k<true><<<dim3(32,16),256,0,stream>>>(Abuf, BT1[it&1], Wl1a, Wl1b,
                Wx1a, Wx1b, We1a, xaB, BT1[(it+1)&1], uaB, ubB);
    }
    x2_k<<<dim3(16,BATCH),256,0,stream>>>(uaB, ubB, Wx2, x2B);
    binit_k<<<dim3(12,128,BATCH),256,0,stream>>>(g0, We2, BT2[0], 128);
    for(int it=0; it<5; it++){
        if(it<4)
            fused2_k<false><<<dim3(32,16),256,0,stream>>>(Abuf, BT2[it&1], Wl2, x2B,
                We2, WQ, BT2[(it+1)&1], out);
        else
            fused2_k<true><<<dim3(32,16),256,0,stream>>>(Abuf, BT2[it&1], Wl2, x2B,
                We2, WQ, BT2[(it+1)&1], out);
    }
}

// Round 5
// 693.293 us; speedup vs baseline: 1.0736x; 1.0736x over previous
//
#include <hip/hip_runtime.h>

// ---- problem constants ----
#define BATCH 16
#define RB    8
#define CITIES 1023
#define NODES 1024
#define HDIM  64
#define H2DIM 128
#define KTOT  3072          // 3 poly terms * 1024 (c padded to 1024)

// sigmoid(x) ~= 0.5 + C1*x + C3*x^3 on [-1,1], max err ~1.3e-4
#define C1f 0.24944119f
#define C3f (-0.01850586f)

typedef __bf16    bf16x8 __attribute__((ext_vector_type(8)));
typedef _Float16  f16x8  __attribute__((ext_vector_type(8)));
typedef _Float16  f16x2  __attribute__((ext_vector_type(2)));
typedef float     f32x4  __attribute__((ext_vector_type(4)));

__device__ __forceinline__ f32x4 mfma16(bf16x8 a, bf16x8 b, f32x4 c){
    return __builtin_amdgcn_mfma_f32_16x16x32_bf16(a, b, c, 0, 0, 0);
}
__device__ __forceinline__ f32x4 mfma16h(f16x8 a, f16x8 b, f32x4 c){
    return __builtin_amdgcn_mfma_f32_16x16x32_f16(a, b, c, 0, 0, 0);
}
__device__ __forceinline__ unsigned short f2b(float f){
    __bf16 b = (__bf16)f;
    return __builtin_bit_cast(unsigned short, b);
}
__device__ __forceinline__ float b2f(unsigned short u){
    unsigned int t = ((unsigned int)u) << 16;
    return __builtin_bit_cast(float, t);
}
__device__ __forceinline__ unsigned short f2h(float f){
    _Float16 h = (_Float16)f;
    return __builtin_bit_cast(unsigned short, h);
}
__device__ __forceinline__ float h2f(unsigned short u){
    return (float)__builtin_bit_cast(_Float16, u);
}
__device__ __forceinline__ void async16(const void* g, void* l){
    __builtin_amdgcn_global_load_lds(
        (const __attribute__((address_space(1))) unsigned int*)g,
        (__attribute__((address_space(3))) unsigned int*)l, 16, 0, 0);
}
template<int N>
__device__ __forceinline__ void wait_vmcnt(){
    asm volatile("s_waitcnt vmcnt(%0)" :: "i"(N) : "memory");
}

// ---------------- kernel: x_a[b,n] = max_r x_a_state*(assign_prev+action) ----------------
__global__ __launch_bounds__(256) void xa_k(const float* __restrict__ xs,
        const float* __restrict__ ap, const float* __restrict__ act,
        float* __restrict__ xa){
    int idx = blockIdx.x*256 + threadIdx.x;       // 16384
    int b = idx >> 10, n = idx & 1023;
    float m = -1e30f;
    #pragma unroll
    for(int r=0;r<RB;r++){
        size_t o = (((size_t)b*RB + r)<<10) + n;
        m = fmaxf(m, xs[o]*(ap[o]+act[o]));
    }
    xa[idx] = m;
}

// ---------------- presence MLP + softmax; 128 thr, 8 pts/thread in registers -------------
__global__ __launch_bounds__(128) void presence_k(const float* __restrict__ edge,
        const float* __restrict__ W1, const float* __restrict__ W2,
        const float* __restrict__ avail,
        unsigned short* __restrict__ P, unsigned short* __restrict__ D){
    int c = blockIdx.x, b = blockIdx.y;
    int tid = threadIdx.x;
    __shared__ f16x8 Wpk[32];    // per h-pair: {wx0,wx1, wy0,wy1, wz0,wz1, w2_0,w2_1}
    __shared__ float red[2];
    if(tid < 32){
        int h0 = tid*2;
        f16x8 w;
        w[0]=(_Float16)W1[h0];       w[1]=(_Float16)W1[h0+1];
        w[2]=(_Float16)W1[64+h0];    w[3]=(_Float16)W1[64+h0+1];
        w[4]=(_Float16)W1[128+h0];   w[5]=(_Float16)W1[128+h0+1];
        w[6]=(_Float16)W2[h0];       w[7]=(_Float16)W2[h0+1];
        Wpk[tid] = w;
    }
    __syncthreads();
    f16x2 e0d[8], e1d[8], e2d[8];
    float acc[8];
    size_t ebase = (((size_t)b*CITIES + c)<<10)*3;
    #pragma unroll
    for(int j=0;j<8;j++){
        int n = tid + j*128;
        size_t ea = ebase + (size_t)n*3;
        _Float16 v0=(_Float16)edge[ea], v1=(_Float16)edge[ea+1], v2=(_Float16)edge[ea+2];
        e0d[j]=(f16x2){v0,v0}; e1d[j]=(f16x2){v1,v1}; e2d[j]=(f16x2){v2,v2};
        acc[j]=0.f;
    }
    const f16x2 z2 = {(_Float16)0, (_Float16)0};
    for(int hp=0;hp<32;hp++){
        f16x8 w = Wpk[hp];
        f16x2 wx={w[0],w[1]}, wy={w[2],w[3]}, wz={w[4],w[5]}, w2={w[6],w[7]};
        #pragma unroll
        for(int j=0;j<8;j++){
            f16x2 a = e0d[j]*wx + e1d[j]*wy + e2d[j]*wz;
            a = __builtin_elementwise_max(a, z2);
            acc[j] = __builtin_amdgcn_fdot2(a, w2, acc[j], false);
        }
    }
    float lg[8], ex[8];
    #pragma unroll
    for(int j=0;j<8;j++){
        int n = tid + j*128;
        float h2 = fmaxf(acc[j], 0.f);             // relu; /TAU with TAU=1
        float mk = (n==c) ? 0.f : avail[(b<<10)+n];
        lg[j] = h2*mk - (1.f-mk)*1e10f;
    }
    int wv = tid>>6, ln = tid&63;
    float mx = -1e30f;
    #pragma unroll
    for(int j=0;j<8;j++) mx = fmaxf(mx, lg[j]);
    for(int o=32;o>0;o>>=1) mx = fmaxf(mx, __shfl_xor(mx,o,64));
    if(ln==0) red[wv]=mx;
    __syncthreads();
    mx = fmaxf(red[0],red[1]);
    __syncthreads();
    float s = 0.f;
    #pragma unroll
    for(int j=0;j<8;j++){ ex[j] = __expf(lg[j]-mx); s += ex[j]; }
    for(int o=32;o>0;o>>=1) s += __shfl_xor(s,o,64);
    if(ln==0) red[wv]=s;
    __syncthreads();
    s = red[0]+red[1];
    float inv = 1.f/s;
    size_t pbase = ((size_t)b*CITIES + c)<<10;
    #pragma unroll
    for(int j=0;j<8;j++){
        int n = tid + j*128;
        P[pbase+n] = f2h(ex[j]*inv);
        D[pbase+n] = __builtin_bit_cast(unsigned short, e0d[j][0]);
    }
}

// ------- build A' [b][i][3*1024] fp16 = {p, p*d, p*d^3} transposed -----------------------
__global__ __launch_bounds__(256) void abuild_k(const unsigned short* __restrict__ P,
        const unsigned short* __restrict__ D, unsigned short* __restrict__ A){
    int ct = blockIdx.x, nt = blockIdx.y, b = blockIdx.z;
    int tid = threadIdx.x;
    __shared__ unsigned short Pt[32][36];
    __shared__ unsigned short Dt[32][36];
    {
        int crow = tid>>3, ng = (tid&7)<<2;
        int c = ct*32 + crow;
        if(c < CITIES){
            size_t o = (((size_t)b*CITIES + c)<<10) + nt*32 + ng;
            *(ushort4*)&Pt[crow][ng] = *(const ushort4*)&P[o];
            *(ushort4*)&Dt[crow][ng] = *(const ushort4*)&D[o];
        } else {
            ushort4 z; z.x=0;z.y=0;z.z=0;z.w=0;
            *(ushort4*)&Pt[crow][ng] = z;
            *(ushort4*)&Dt[crow][ng] = z;
        }
    }
    __syncthreads();
    int nrow = tid>>3, cg = (tid&7)<<2;
    ushort4 w0, w1, w2;
    #pragma unroll
    for(int j=0;j<4;j++){
        float p = h2f(Pt[cg+j][nrow]);
        float d = h2f(Dt[cg+j][nrow]);
        float d3 = d*d*d;
        ((unsigned short*)&w0)[j] = f2h(p);
        ((unsigned short*)&w1)[j] = f2h(p*d);
        ((unsigned short*)&w2)[j] = f2h(p*d3);
    }
    size_t abase = ((size_t)(b<<10) + nt*32 + nrow)*KTOT + ct*32 + cg;
    *(ushort4*)&A[abase]      = w0;
    *(ushort4*)&A[abase+1024] = w1;
    *(ushort4*)&A[abase+2048] = w2;
}

// ---------------- initial B'^T [b][h][kc] = q_k(h) * U0[b][c][h] (fp16) ------------------
__global__ __launch_bounds__(256) void binit_k(const float* __restrict__ U0,
        const float* __restrict__ We, unsigned short* __restrict__ BT, int nout){
    int kc = blockIdx.x*256 + threadIdx.x;   // 0..3071
    int h = blockIdx.y, b = blockIdx.z;
    int k = kc >> 10, c = kc & 1023;
    float we = We[h];
    float q = (k==0) ? 0.5f : (k==1 ? C1f*we : C3f*we*we*we);
    float u = (c < CITIES) ? U0[(((size_t)b<<10) + c)*nout + h] : 0.f;
    BT[((size_t)(b*nout + h))*KTOT + kc] = f2h(q*u);
}

#define SR 72

// XCD-exclusive batch swizzle: under round-robin (id%8 -> XCD) dispatch, batches 2x,2x+1
// land on XCD x only -> per-XCD B' working set 2 tiles (<=1.5 MB) fits 4 MB L2.
__device__ __forceinline__ void decode_swz(int id, int& mt, int& b){
    int bh = id & 7, j = id >> 3;
    b = (bh<<1) | (j>>5);
    mt = j & 31;
}

// ======== fused T1: full-K GEMM (M=32, N=64, K=3072) + reduce1 epilogue ==================
// 512 blocks, 256 thr, 2 blocks/CU (LDS 36 KB). Waves 2x2: 16 rows x 32 cols.
// 3-buffer ring, counted vmcnt(3) + raw s_barrier.
template<bool LAST>
__global__ __launch_bounds__(256) void fused1_k(const unsigned short* __restrict__ Ap,
        const unsigned short* __restrict__ BT,
        const float* __restrict__ Wl1a, const float* __restrict__ Wl1b,
        const float* __restrict__ Wx1a, const float* __restrict__ Wx1b,
        const float* __restrict__ We1a, const float* __restrict__ xa,
        unsigned short* __restrict__ Bnext, float* __restrict__ ua, float* __restrict__ ub){
    int mt, b; decode_swz(blockIdx.x, mt, b);
    int i0 = mt*32;
    int tid = threadIdx.x, wave=tid>>6, lane=tid&63, quad=lane>>4, l16=lane&15;
    int wm = wave>>1, wn = wave&1;
    // ring: 3 x 12288 B (A 4K + B 8K); epilogue aliases first 27648 B
    __shared__ __align__(16) char smem[36864];
    unsigned short* Lh = (unsigned short*)smem;             // 32*SR*2 = 4608
    unsigned short* Ll = (unsigned short*)(smem + 4608);
    unsigned short* Wh = (unsigned short*)(smem + 9216);    // 64*SR*2 = 9216
    unsigned short* Wo = (unsigned short*)(smem + 18432);

    f32x4 zero = {0.f,0.f,0.f,0.f};
    f32x4 gacc[2] = {zero,zero};
    const unsigned short* pa;
    const unsigned short* pb[2];
    {
        int r = tid>>3, ch = tid&7;
        pa = Ap + ((size_t)(b<<10) + i0 + r)*KTOT + ((ch ^ (r&7))<<3);
    }
    #pragma unroll
    for(int rd=0; rd<2; rd++){
        int idx = rd*256 + tid, r = idx>>3, ch = idx&7;
        pb[rd] = BT + ((size_t)b*64 + r)*KTOT + ((ch ^ (r&7))<<3);
    }
    int sw = l16&7;
    auto stage = [&](char* buf){
        unsigned short* At = (unsigned short*)buf;
        unsigned short* Bt = At + 2048;
        async16(pa, At + tid*8); pa += 64;
        #pragma unroll
        for(int rd=0; rd<2; rd++){ async16(pb[rd], Bt + rd*2048 + tid*8); pb[rd] += 64; }
    };
    auto comp = [&](const char* buf){
        const unsigned short* At = (const unsigned short*)buf;
        const unsigned short* Bt = At + 2048;
        #pragma unroll
        for(int kb=0; kb<2; kb++){
            f16x8 af = *(const f16x8*)&At[(wm*16 + l16)*64 + (((kb*4+quad)^sw)<<3)];
            #pragma unroll
            for(int nt2=0; nt2<2; nt2++){
                f16x8 bf = *(const f16x8*)&Bt[(wn*32 + nt2*16 + l16)*64 + (((kb*4+quad)^sw)<<3)];
                gacc[nt2] = mfma16h(af, bf, gacc[nt2]);
            }
        }
    };
    char* b0 = smem; char* b1 = smem + 12288; char* b2 = smem + 24576;
    stage(b0); stage(b1);                       // 6 loads/thread in flight
    wait_vmcnt<3>(); __builtin_amdgcn_s_barrier();
    for(int kk=0; kk<46; kk++){
        stage(b2);
        comp(b0);
        wait_vmcnt<3>(); __builtin_amdgcn_s_barrier();
        char* tp=b0; b0=b1; b1=b2; b2=tp;
    }
    comp(b0);
    wait_vmcnt<0>(); __builtin_amdgcn_s_barrier();
    comp(b1);
    __syncthreads();
    // ---- epilogue: write l (hi/lo bf16) to LDS, load W_l, small MFMA, relu, emit ----
    #pragma unroll
    for(int nt2=0; nt2<2; nt2++){
        int h = wn*32 + nt2*16 + l16;
        #pragma unroll
        for(int rr=0; rr<4; rr++){
            int i = wm*16 + quad*4 + rr;
            float v = gacc[nt2][rr];
            unsigned short hh = f2b(v);
            Lh[i*SR + h] = hh;
            Ll[i*SR + h] = f2b(v - b2f(hh));
        }
    }
    {
        int k = tid>>2, n0 = (tid&3)*16;
        for(int j=0;j<16;j++){
            float w = Wl1a[k*64 + n0 + j];
            unsigned short hh = f2b(w);
            Wh[(n0+j)*SR + k] = hh;
            Wo[(n0+j)*SR + k] = f2b(w - b2f(hh));
        }
    }
    __syncthreads();
    f32x4 acc[2] = {zero,zero};
    #pragma unroll
    for(int kc=0;kc<2;kc++){
        bf16x8 ah = *(const bf16x8*)&Lh[(wm*16+l16)*SR + kc*32 + quad*8];
        bf16x8 al = *(const bf16x8*)&Ll[(wm*16+l16)*SR + kc*32 + quad*8];
        #pragma unroll
        for(int nt2=0;nt2<2;nt2++){
            bf16x8 bh = *(const bf16x8*)&Wh[(wn*32+nt2*16+l16)*SR + kc*32 + quad*8];
            bf16x8 bl = *(const bf16x8*)&Wo[(wn*32+nt2*16+l16)*SR + kc*32 + quad*8];
            acc[nt2] = mfma16(ah, bh, acc[nt2]);
            acc[nt2] = mfma16(ah, bl, acc[nt2]);
            acc[nt2] = mfma16(al, bh, acc[nt2]);
        }
    }
    int gi = i0 + wm*16 + quad*4;
    float4 xav = *(const float4*)&xa[(b<<10) + gi];
    float xr[4] = {xav.x, xav.y, xav.z, xav.w};
    if(!LAST){
        #pragma unroll
        for(int nt2=0;nt2<2;nt2++){
            int h = wn*32 + nt2*16 + l16;
            float wx = Wx1a[h];
            float we = We1a[h];
            float q1 = C1f*we, q2 = C3f*we*we*we;
            ushort4 w0,w1,w2;
            #pragma unroll
            for(int rr=0;rr<4;rr++){
                float u = fmaxf(acc[nt2][rr] + xr[rr]*wx, 0.f);
                bool pad = (gi+rr == 1023);
                ((unsigned short*)&w0)[rr] = pad?(unsigned short)0:f2h(0.5f*u);
                ((unsigned short*)&w1)[rr] = pad?(unsigned short)0:f2h(q1*u);
                ((unsigned short*)&w2)[rr] = pad?(unsigned short)0:f2h(q2*u);
            }
            size_t base = ((size_t)(b*64 + h))*KTOT + gi;
            *(ushort4*)&Bnext[base]      = w0;
            *(ushort4*)&Bnext[base+1024] = w1;
            *(ushort4*)&Bnext[base+2048] = w2;
        }
    } else {
        #pragma unroll
        for(int nt2=0;nt2<2;nt2++){
            int h = wn*32 + nt2*16 + l16; float wx = Wx1a[h];
            #pragma unroll
            for(int rr=0;rr<4;rr++)
                ua[(((size_t)b<<10)+gi+rr)*64 + h] = fmaxf(acc[nt2][rr] + xr[rr]*wx, 0.f);
        }
        __syncthreads();
        { int k = tid>>2, n0 = (tid&3)*16;
          for(int j=0;j<16;j++){
              float w = Wl1b[k*64 + n0 + j];
              unsigned short hh = f2b(w);
              Wh[(n0+j)*SR + k] = hh;
              Wo[(n0+j)*SR + k] = f2b(w - b2f(hh));
          } }
        __syncthreads();
        f32x4 acc2[2] = {zero,zero};
        #pragma unroll
        for(int kc=0;kc<2;kc++){
            bf16x8 ah = *(const bf16x8*)&Lh[(wm*16+l16)*SR + kc*32 + quad*8];
            bf16x8 al = *(const bf16x8*)&Ll[(wm*16+l16)*SR + kc*32 + quad*8];
            #pragma unroll
            for(int nt2=0;nt2<2;nt2++){
                bf16x8 bh = *(const bf16x8*)&Wh[(wn*32+nt2*16+l16)*SR + kc*32 + quad*8];
                bf16x8 bl = *(const bf16x8*)&Wo[(wn*32+nt2*16+l16)*SR + kc*32 + quad*8];
                acc2[nt2] = mfma16(ah, bh, acc2[nt2]);
                acc2[nt2] = mfma16(ah, bl, acc2[nt2]);
                acc2[nt2] = mfma16(al, bh, acc2[nt2]);
            }
        }
        #pragma unroll
        for(int nt2=0;nt2<2;nt2++){
            int h = wn*32 + nt2*16 + l16; float wx = Wx1b[h];
            #pragma unroll
            for(int rr=0;rr<4;rr++)
                ub[(((size_t)b<<10)+gi+rr)*64 + h] = fmaxf(acc2[nt2][rr] + xr[rr]*wx, 0.f);
        }
    }
}

// ---------------- x2 = concat(ua,ub) @ W_x_2  (hi/lo MFMA, 2 K-phases) -------------------
__global__ __launch_bounds__(256) void x2_k(const float* __restrict__ ua,
        const float* __restrict__ ub, const float* __restrict__ Wx2,
        float* __restrict__ x2){
    int mt = blockIdx.x, b = blockIdx.y;
    int i0 = mt*64;
    int tid = threadIdx.x, wave=tid>>6, lane=tid&63, quad=lane>>4, l16=lane&15;
    __shared__ __align__(16) unsigned short Uh[64*SR], Ul[64*SR];
    __shared__ __align__(16) unsigned short Wh[128*SR], Wo[128*SR];
    f32x4 zero = {0.f,0.f,0.f,0.f};
    f32x4 acc[8];
    #pragma unroll
    for(int nt=0;nt<8;nt++) acc[nt]=zero;
    for(int ph=0; ph<2; ph++){
        if(ph) __syncthreads();
        {
            int k = tid>>2, n0 = (tid&3)*32;
            for(int j=0;j<32;j++){
                float w = Wx2[(ph*64 + k)*128 + n0 + j];
                unsigned short hh = f2b(w);
                Wh[(n0+j)*SR + k] = hh;
                Wo[(n0+j)*SR + k] = f2b(w - b2f(hh));
            }
            int i = tid>>2, c0 = (tid&3)*16;
            const float* src = (ph ? ub : ua) + (((size_t)b<<10)+i0+i)*64 + c0;
            #pragma unroll
            for(int j=0;j<4;j++){
                float4 v = *(const float4*)(src + j*4);
                float vv[4] = {v.x, v.y, v.z, v.w};
                #pragma unroll
                for(int t=0;t<4;t++){
                    unsigned short hh = f2b(vv[t]);
                    Uh[i*SR + c0 + j*4 + t] = hh;
                    Ul[i*SR + c0 + j*4 + t] = f2b(vv[t] - b2f(hh));
                }
            }
        }
        __syncthreads();
        #pragma unroll
        for(int kc=0;kc<2;kc++){
            bf16x8 ah = *(const bf16x8*)&Uh[(wave*16+l16)*SR + kc*32 + quad*8];
            bf16x8 al = *(const bf16x8*)&Ul[(wave*16+l16)*SR + kc*32 + quad*8];
            #pragma unroll
            for(int nt=0;nt<8;nt++){
                bf16x8 bh = *(const bf16x8*)&Wh[(nt*16+l16)*SR + kc*32 + quad*8];
                bf16x8 bl = *(const bf16x8*)&Wo[(nt*16+l16)*SR + kc*32 + quad*8];
                acc[nt] = mfma16(ah, bh, acc[nt]);
                acc[nt] = mfma16(ah, bl, acc[nt]);
                acc[nt] = mfma16(al, bh, acc[nt]);
            }
        }
    }
    int gi = i0 + wave*16 + quad*4;
    #pragma unroll
    for(int nt=0;nt<8;nt++){
        int h = nt*16 + l16;
        #pragma unroll
        for(int rr=0;rr<4;rr++)
            x2[(((size_t)b<<10)+gi+rr)*128 + h] = acc[nt][rr];
    }
}

// ======== fused T2: full-K GEMM (M=32, N=128, K=3072) + reduce2 epilogue =================
// 512 blocks, 2 blocks/CU (LDS 60 KB). Waves 2x2: 16 rows x 64 cols.
// 3-buffer ring (3 x 20480 B), counted vmcnt(5).
template<bool LAST>
__global__ __launch_bounds__(256) void fused2_k(const unsigned short* __restrict__ Ap,
        const unsigned short* __restrict__ BT,
        const float* __restrict__ Wl2, const float* __restrict__ x2,
        const float* __restrict__ We2, const float* __restrict__ WQ,
        unsigned short* __restrict__ Bnext, float* __restrict__ out){
    int mt, b; decode_swz(blockIdx.x, mt, b);
    int i0 = mt*32;
    int tid = threadIdx.x, wave=tid>>6, lane=tid&63, quad=lane>>4, l16=lane&15;
    int wm = wave>>1, wn = wave&1;
    __shared__ __align__(16) char smem[61440];
    __shared__ float red[4];
    unsigned short* Lh = (unsigned short*)smem;             // 32*SR*2 = 4608
    unsigned short* Ll = (unsigned short*)(smem + 4608);
    unsigned short* Wh = (unsigned short*)(smem + 9216);    // 128*SR*2 = 18432
    unsigned short* Wo = (unsigned short*)(smem + 27648);   // ends 46080

    f32x4 zero = {0.f,0.f,0.f,0.f};
    f32x4 gacc[4] = {zero,zero,zero,zero};
    const unsigned short* pa;
    const unsigned short* pb[4];
    {
        int r = tid>>3, ch = tid&7;
        pa = Ap + ((size_t)(b<<10) + i0 + r)*KTOT + ((ch ^ (r&7))<<3);
    }
    #pragma unroll
    for(int rd=0; rd<4; rd++){
        int idx = rd*256 + tid, r = idx>>3, ch = idx&7;
        pb[rd] = BT + ((size_t)b*128 + r)*KTOT + ((ch ^ (r&7))<<3);
    }
    int sw = l16&7;
    auto stage = [&](char* buf){
        unsigned short* At = (unsigned short*)buf;
        unsigned short* Bt = At + 2048;
        async16(pa, At + tid*8); pa += 64;
        #pragma unroll
        for(int rd=0; rd<4; rd++){ async16(pb[rd], Bt + rd*2048 + tid*8); pb[rd] += 64; }
    };
    auto comp = [&](const char* buf){
        const unsigned short* At = (const unsigned short*)buf;
        const unsigned short* Bt = At + 2048;
        #pragma unroll
        for(int kb=0; kb<2; kb++){
            f16x8 af = *(const f16x8*)&At[(wm*16 + l16)*64 + (((kb*4+quad)^sw)<<3)];
            #pragma unroll
            for(int nt=0; nt<4; nt++){
                f16x8 bf = *(const f16x8*)&Bt[(wn*64 + nt*16 + l16)*64 + (((kb*4+quad)^sw)<<3)];
                gacc[nt] = mfma16h(af, bf, gacc[nt]);
            }
        }
    };
    char* b0 = smem; char* b1 = smem + 20480; char* b2 = smem + 40960;
    stage(b0); stage(b1);                       // 10 loads/thread in flight
    wait_vmcnt<5>(); __builtin_amdgcn_s_barrier();
    for(int kk=0; kk<46; kk++){
        stage(b2);
        comp(b0);
        wait_vmcnt<5>(); __builtin_amdgcn_s_barrier();
        char* tp=b0; b0=b1; b1=b2; b2=tp;
    }
    comp(b0);
    wait_vmcnt<0>(); __builtin_amdgcn_s_barrier();
    comp(b1);
    __syncthreads();
    // ---- epilogue: 2 phases over k-halves; waves with wn==ph own that l-half ----
    f32x4 fac[4] = {zero,zero,zero,zero};
    #pragma unroll
    for(int ph=0; ph<2; ph++){
        if(ph) __syncthreads();
        if(wn == ph){
            #pragma unroll
            for(int nt=0; nt<4; nt++){
                int hh_col = nt*16 + l16;
                #pragma unroll
                for(int rr=0; rr<4; rr++){
                    int i = wm*16 + quad*4 + rr;
                    float v = gacc[nt][rr];
                    unsigned short hh = f2b(v);
                    Lh[i*SR + hh_col] = hh;
                    Ll[i*SR + hh_col] = f2b(v - b2f(hh));
                }
            }
        }
        {
            int k = tid>>2, n0 = (tid&3)*32;
            for(int j=0;j<32;j++){
                float w = Wl2[(ph*64 + k)*128 + n0 + j];
                unsigned short hh = f2b(w);
                Wh[(n0+j)*SR + k] = hh;
                Wo[(n0+j)*SR + k] = f2b(w - b2f(hh));
            }
        }
        __syncthreads();
        #pragma unroll
        for(int kc=0;kc<2;kc++){
            bf16x8 ah = *(const bf16x8*)&Lh[(wm*16+l16)*SR + kc*32 + quad*8];
            bf16x8 al = *(const bf16x8*)&Ll[(wm*16+l16)*SR + kc*32 + quad*8];
            #pragma unroll
            for(int nt=0;nt<4;nt++){
                bf16x8 bh = *(const bf16x8*)&Wh[(wn*64+nt*16+l16)*SR + kc*32 + quad*8];
                bf16x8 bl = *(const bf16x8*)&Wo[(wn*64+nt*16+l16)*SR + kc*32 + quad*8];
                fac[nt] = mfma16(ah, bh, fac[nt]);
                fac[nt] = mfma16(ah, bl, fac[nt]);
                fac[nt] = mfma16(al, bh, fac[nt]);
            }
        }
    }
    int gi = i0 + wm*16 + quad*4;
    float qp = 0.f;
    #pragma unroll
    for(int nt=0;nt<4;nt++){
        int h = wn*64 + nt*16 + l16;
        float g[4];
        #pragma unroll
        for(int rr=0;rr<4;rr++)
            g[rr] = fmaxf(fac[nt][rr] + x2[(((size_t)b<<10)+gi+rr)*128 + h], 0.f);
        if(!LAST){
            float we = We2[h];
            float q1 = C1f*we, q2 = C3f*we*we*we;
            ushort4 w0,w1,w2;
            #pragma unroll
            for(int rr=0;rr<4;rr++){
                bool pad = (gi+rr == 1023);
                ((unsigned short*)&w0)[rr] = pad?(unsigned short)0:f2h(0.5f*g[rr]);
                ((unsigned short*)&w1)[rr] = pad?(unsigned short)0:f2h(q1*g[rr]);
                ((unsigned short*)&w2)[rr] = pad?(unsigned short)0:f2h(q2*g[rr]);
            }
            size_t base = ((size_t)(b*128 + h))*KTOT + gi;
            *(ushort4*)&Bnext[base]      = w0;
            *(ushort4*)&Bnext[base+1024] = w1;
            *(ushort4*)&Bnext[base+2048] = w2;
        } else {
            float wq = WQ[h];
            #pragma unroll
            for(int rr=0;rr<4;rr++) qp = fmaf(g[rr], wq, qp);
        }
    }
    if(LAST){
        for(int o=32;o>0;o>>=1) qp += __shfl_xor(qp,o,64);
        if(lane==0) red[wave]=qp;
        __syncthreads();
        if(tid==0) atomicAdd(&out[b], red[0]+red[1]+red[2]+red[3]);
    }
}

// ---------------- host launch ------------------------------------------------------------
extern "C" void kernel_launch(void* const* d_in, const int* in_sizes, int n_in,
                              void* d_out, int out_size, void* d_ws, size_t ws_size,
                              hipStream_t stream){
    (void)in_sizes; (void)n_in; (void)out_size; (void)ws_size;
    const float* xs   = (const float*)d_in[0];
    const float* ap   = (const float*)d_in[1];
    const float* act  = (const float*)d_in[2];
    const float* edge = (const float*)d_in[3];
    const float* avail= (const float*)d_in[4];
    const float* ua0  = (const float*)d_in[5];
    const float* g0   = (const float*)d_in[7];
    const float* W1p  = (const float*)d_in[8];
    const float* W2p  = (const float*)d_in[9];
    const float* Wx1a = (const float*)d_in[10];
    const float* We1a = (const float*)d_in[11];
    const float* Wl1a = (const float*)d_in[12];
    const float* Wx1b = (const float*)d_in[13];
    const float* Wl1b = (const float*)d_in[15];
    const float* Wx2  = (const float*)d_in[16];
    const float* We2  = (const float*)d_in[17];
    const float* Wl2  = (const float*)d_in[18];
    const float* WQ   = (const float*)d_in[19];
    float* out = (float*)d_out;

    char* ws = (char*)d_ws;
    // A' (persistent): 16*1024*3072*2 = 100,663,296 B
    unsigned short* Abuf = (unsigned short*)ws;
    char* r2 = ws + 100663296;
    // P/D (fp16) live only until abuild; aliased with B' buffers after:
    unsigned short* Pbuf = (unsigned short*)r2;                      // 33,521,664
    unsigned short* Dbuf = (unsigned short*)(r2 + 33521664);         // 33,521,664 (ends 67,043,328)
    unsigned short* BT1a = (unsigned short*)r2;                      //  6,291,456
    unsigned short* BT1b = (unsigned short*)(r2 + 6291456);          //  6,291,456
    unsigned short* BT2a = (unsigned short*)(r2 + 12582912);         // 12,582,912
    unsigned short* BT2b = (unsigned short*)(r2 + 25165824);         // 12,582,912 (ends 37,748,736)
    float* uaB           = (float*)(r2 + 117440512);                 //  4,194,304
    float* ubB           = (float*)(r2 + 121634816);                 //  4,194,304
    float* x2B           = (float*)(r2 + 125829120);                 //  8,388,608
    float* xaB           = (float*)(r2 + 134217728);                 //     65,536
    unsigned short* BT1[2] = {BT1a, BT1b};
    unsigned short* BT2[2] = {BT2a, BT2b};

    hipMemsetAsync(d_out, 0, BATCH*sizeof(float), stream);
    xa_k<<<64,256,0,stream>>>(xs, ap, act, xaB);
    presence_k<<<dim3(CITIES,BATCH),128,0,stream>>>(edge, W1p, W2p, avail, Pbuf, Dbuf);
    abuild_k<<<dim3(32,32,BATCH),256,0,stream>>>(Pbuf, Dbuf, Abuf);
    binit_k<<<dim3(12,64,BATCH),256,0,stream>>>(ua0, We1a, BT1[0], 64);
    for(int it=0; it<5; it++){
        if(it<4)
            fused1_k<false><<<512,256,0,stream>>>(Abuf, BT1[it&1], Wl1a, Wl1b,
                Wx1a, Wx1b, We1a, xaB, BT1[(it+1)&1], uaB, ubB);
        else
            fused1_k<true><<<512,256,0,stream>>>(Abuf, BT1[it&1], Wl1a, Wl1b,
                Wx1a, Wx1b, We1a, xaB, BT1[(it+1)&1], uaB, ubB);
    }
    x2_k<<<dim3(16,BATCH),256,0,stream>>>(uaB, ubB, Wx2, x2B);
    binit_k<<<dim3(12,128,BATCH),256,0,stream>>>(g0, We2, BT2[0], 128);
    for(int it=0; it<5; it++){
        if(it<4)
            fused2_k<false><<<512,256,0,stream>>>(Abuf, BT2[it&1], Wl2, x2B,
                We2, WQ, BT2[(it+1)&1], out);
        else
            fused2_k<true><<<512,256,0,stream>>>(Abuf, BT2[it&1], Wl2, x2B,
                We2, WQ, BT2[(it+1)&1], out);
    }
}

// Round 6
// 652.660 us; speedup vs baseline: 1.1404x; 1.0623x over previous
//
#include <hip/hip_runtime.h>

// ---- problem constants ----
#define BATCH 16
#define RB    8
#define CITIES 1023
#define NODES 1024
#define HDIM  64
#define H2DIM 128
#define KTOT  3072          // 3 poly terms * 1024 (c padded to 1024)

// sigmoid(x) ~= 0.5 + C1*x + C3*x^3 on [-1,1], max err ~1.3e-4
#define C1f 0.24944119f
#define C3f (-0.01850586f)

typedef __bf16    bf16x8 __attribute__((ext_vector_type(8)));
typedef _Float16  f16x8  __attribute__((ext_vector_type(8)));
typedef _Float16  f16x2  __attribute__((ext_vector_type(2)));
typedef float     f32x4  __attribute__((ext_vector_type(4)));

__device__ __forceinline__ f32x4 mfma16(bf16x8 a, bf16x8 b, f32x4 c){
    return __builtin_amdgcn_mfma_f32_16x16x32_bf16(a, b, c, 0, 0, 0);
}
__device__ __forceinline__ f32x4 mfma16h(f16x8 a, f16x8 b, f32x4 c){
    return __builtin_amdgcn_mfma_f32_16x16x32_f16(a, b, c, 0, 0, 0);
}
__device__ __forceinline__ unsigned short f2b(float f){
    __bf16 b = (__bf16)f;
    return __builtin_bit_cast(unsigned short, b);
}
__device__ __forceinline__ float b2f(unsigned short u){
    unsigned int t = ((unsigned int)u) << 16;
    return __builtin_bit_cast(float, t);
}
__device__ __forceinline__ unsigned short f2h(float f){
    _Float16 h = (_Float16)f;
    return __builtin_bit_cast(unsigned short, h);
}
__device__ __forceinline__ float h2f(unsigned short u){
    return (float)__builtin_bit_cast(_Float16, u);
}
__device__ __forceinline__ void async16(const void* g, void* l){
    __builtin_amdgcn_global_load_lds(
        (const __attribute__((address_space(1))) unsigned int*)g,
        (__attribute__((address_space(3))) unsigned int*)l, 16, 0, 0);
}
template<int N>
__device__ __forceinline__ void wait_vmcnt(){
    asm volatile("s_waitcnt vmcnt(%0)" :: "i"(N) : "memory");
}

// ---------------- kernel: x_a[b,n] = max_r x_a_state*(assign_prev+action) ----------------
__global__ __launch_bounds__(256) void xa_k(const float* __restrict__ xs,
        const float* __restrict__ ap, const float* __restrict__ act,
        float* __restrict__ xa){
    int idx = blockIdx.x*256 + threadIdx.x;       // 16384
    int b = idx >> 10, n = idx & 1023;
    float m = -1e30f;
    #pragma unroll
    for(int r=0;r<RB;r++){
        size_t o = (((size_t)b*RB + r)<<10) + n;
        m = fmaxf(m, xs[o]*(ap[o]+act[o]));
    }
    xa[idx] = m;
}

// ---------------- presence MLP + softmax; 128 thr, 8 pts/thread in registers -------------
__global__ __launch_bounds__(128) void presence_k(const float* __restrict__ edge,
        const float* __restrict__ W1, const float* __restrict__ W2,
        const float* __restrict__ avail,
        unsigned short* __restrict__ P, unsigned short* __restrict__ D){
    int c = blockIdx.x, b = blockIdx.y;
    int tid = threadIdx.x;
    __shared__ f16x8 Wpk[32];    // per h-pair: {wx0,wx1, wy0,wy1, wz0,wz1, w2_0,w2_1}
    __shared__ float red[2];
    if(tid < 32){
        int h0 = tid*2;
        f16x8 w;
        w[0]=(_Float16)W1[h0];       w[1]=(_Float16)W1[h0+1];
        w[2]=(_Float16)W1[64+h0];    w[3]=(_Float16)W1[64+h0+1];
        w[4]=(_Float16)W1[128+h0];   w[5]=(_Float16)W1[128+h0+1];
        w[6]=(_Float16)W2[h0];       w[7]=(_Float16)W2[h0+1];
        Wpk[tid] = w;
    }
    __syncthreads();
    f16x2 e0d[8], e1d[8], e2d[8];
    float acc[8];
    size_t ebase = (((size_t)b*CITIES + c)<<10)*3;
    #pragma unroll
    for(int j=0;j<8;j++){
        int n = tid + j*128;
        size_t ea = ebase + (size_t)n*3;
        _Float16 v0=(_Float16)edge[ea], v1=(_Float16)edge[ea+1], v2=(_Float16)edge[ea+2];
        e0d[j]=(f16x2){v0,v0}; e1d[j]=(f16x2){v1,v1}; e2d[j]=(f16x2){v2,v2};
        acc[j]=0.f;
    }
    const f16x2 z2 = {(_Float16)0, (_Float16)0};
    for(int hp=0;hp<32;hp++){
        f16x8 w = Wpk[hp];
        f16x2 wx={w[0],w[1]}, wy={w[2],w[3]}, wz={w[4],w[5]}, w2={w[6],w[7]};
        #pragma unroll
        for(int j=0;j<8;j++){
            f16x2 a = e0d[j]*wx + e1d[j]*wy + e2d[j]*wz;
            a = __builtin_elementwise_max(a, z2);
            acc[j] = __builtin_amdgcn_fdot2(a, w2, acc[j], false);
        }
    }
    float lg[8], ex[8];
    #pragma unroll
    for(int j=0;j<8;j++){
        int n = tid + j*128;
        float h2 = fmaxf(acc[j], 0.f);             // relu; /TAU with TAU=1
        float mk = (n==c) ? 0.f : avail[(b<<10)+n];
        lg[j] = h2*mk - (1.f-mk)*1e10f;
    }
    int wv = tid>>6, ln = tid&63;
    float mx = -1e30f;
    #pragma unroll
    for(int j=0;j<8;j++) mx = fmaxf(mx, lg[j]);
    for(int o=32;o>0;o>>=1) mx = fmaxf(mx, __shfl_xor(mx,o,64));
    if(ln==0) red[wv]=mx;
    __syncthreads();
    mx = fmaxf(red[0],red[1]);
    __syncthreads();
    float s = 0.f;
    #pragma unroll
    for(int j=0;j<8;j++){ ex[j] = __expf(lg[j]-mx); s += ex[j]; }
    for(int o=32;o>0;o>>=1) s += __shfl_xor(s,o,64);
    if(ln==0) red[wv]=s;
    __syncthreads();
    s = red[0]+red[1];
    float inv = 1.f/s;
    size_t pbase = ((size_t)b*CITIES + c)<<10;
    #pragma unroll
    for(int j=0;j<8;j++){
        int n = tid + j*128;
        P[pbase+n] = f2h(ex[j]*inv);
        D[pbase+n] = __builtin_bit_cast(unsigned short, e0d[j][0]);
    }
}

// ------- build A' [b][i][3*1024] fp16 = {p, p*d, p*d^3} transposed -----------------------
__global__ __launch_bounds__(256) void abuild_k(const unsigned short* __restrict__ P,
        const unsigned short* __restrict__ D, unsigned short* __restrict__ A){
    int ct = blockIdx.x, nt = blockIdx.y, b = blockIdx.z;
    int tid = threadIdx.x;
    __shared__ unsigned short Pt[32][36];
    __shared__ unsigned short Dt[32][36];
    {
        int crow = tid>>3, ng = (tid&7)<<2;
        int c = ct*32 + crow;
        if(c < CITIES){
            size_t o = (((size_t)b*CITIES + c)<<10) + nt*32 + ng;
            *(ushort4*)&Pt[crow][ng] = *(const ushort4*)&P[o];
            *(ushort4*)&Dt[crow][ng] = *(const ushort4*)&D[o];
        } else {
            ushort4 z; z.x=0;z.y=0;z.z=0;z.w=0;
            *(ushort4*)&Pt[crow][ng] = z;
            *(ushort4*)&Dt[crow][ng] = z;
        }
    }
    __syncthreads();
    int nrow = tid>>3, cg = (tid&7)<<2;
    ushort4 w0, w1, w2;
    #pragma unroll
    for(int j=0;j<4;j++){
        float p = h2f(Pt[cg+j][nrow]);
        float d = h2f(Dt[cg+j][nrow]);
        float d3 = d*d*d;
        ((unsigned short*)&w0)[j] = f2h(p);
        ((unsigned short*)&w1)[j] = f2h(p*d);
        ((unsigned short*)&w2)[j] = f2h(p*d3);
    }
    size_t abase = ((size_t)(b<<10) + nt*32 + nrow)*KTOT + ct*32 + cg;
    *(ushort4*)&A[abase]      = w0;
    *(ushort4*)&A[abase+1024] = w1;
    *(ushort4*)&A[abase+2048] = w2;
}

// ---------------- initial G^T [b][h][c] = U0[b][c][h] (fp16, unscaled) -------------------
__global__ __launch_bounds__(256) void binit_k(const float* __restrict__ U0,
        unsigned short* __restrict__ BT, int nout){
    int c = blockIdx.x*256 + threadIdx.x;   // 0..1023
    int h = blockIdx.y, b = blockIdx.z;
    float u = (c < CITIES) ? U0[(((size_t)b<<10) + c)*nout + h] : 0.f;
    BT[((size_t)(b*nout + h)<<10) + c] = f2h(u);
}

#define SR 72

// XCD-exclusive batch swizzle: under round-robin (id%8 -> XCD) dispatch, batches 2x,2x+1
// land on XCD x only -> per-XCD G working set fits L2.
__device__ __forceinline__ void decode_swz(int id, int& mt, int& b){
    int bh = id & 7, j = id >> 3;
    b = (bh<<1) | (j>>5);
    mt = j & 31;
}

// ======== fused T1: structured-B GEMM (M=32, K=3 phases x 1024) + reduce1 epilogue =======
// B' = q_k(h) * G[c][h]: stage only G (64x1024 fp16, L2-resident); 3 phases of 16 K-steps
// over the same G tiles; per-phase accumulator folded as tot += q_k(h)*pacc.
// 512 blocks, 2/CU (LDS 36 KB); 3-buffer ring, counted vmcnt(3) + raw s_barrier.
template<bool LAST>
__global__ __launch_bounds__(256) void fused1_k(const unsigned short* __restrict__ Ap,
        const unsigned short* __restrict__ BT,
        const float* __restrict__ Wl1a, const float* __restrict__ Wl1b,
        const float* __restrict__ Wx1a, const float* __restrict__ Wx1b,
        const float* __restrict__ We1a, const float* __restrict__ xa,
        unsigned short* __restrict__ Bnext, float* __restrict__ ua, float* __restrict__ ub){
    int mt, b; decode_swz(blockIdx.x, mt, b);
    int i0 = mt*32;
    int tid = threadIdx.x, wave=tid>>6, lane=tid&63, quad=lane>>4, l16=lane&15;
    int wm = wave>>1, wn = wave&1;
    // ring: 3 x 12288 B (A 4K + B 8K); epilogue aliases first 27648 B
    __shared__ __align__(16) char smem[36864];
    unsigned short* Lh = (unsigned short*)smem;             // 32*SR*2 = 4608
    unsigned short* Ll = (unsigned short*)(smem + 4608);
    unsigned short* Wh = (unsigned short*)(smem + 9216);    // 64*SR*2 = 9216
    unsigned short* Wo = (unsigned short*)(smem + 18432);

    f32x4 zero = {0.f,0.f,0.f,0.f};
    f32x4 tot[2] = {zero,zero};
    f32x4 pacc[2] = {zero,zero};
    float q1v[2], q2v[2];
    #pragma unroll
    for(int nt2=0;nt2<2;nt2++){
        float we = We1a[wn*32 + nt2*16 + l16];
        q1v[nt2] = C1f*we; q2v[nt2] = C3f*we*we*we;
    }
    const unsigned short* pa;     // A base (walks t*64)
    const unsigned short* pb[2];  // G base (rewinds every 16 steps)
    {
        int r = tid>>3, ch = tid&7;
        pa = Ap + ((size_t)(b<<10) + i0 + r)*KTOT + ((ch ^ (r&7))<<3);
    }
    #pragma unroll
    for(int rd=0; rd<2; rd++){
        int idx = rd*256 + tid, r = idx>>3, ch = idx&7;
        pb[rd] = BT + (((size_t)(b*64 + r))<<10) + ((ch ^ (r&7))<<3);
    }
    int sw = l16&7;
    auto stage = [&](char* buf, int t){
        unsigned short* At = (unsigned short*)buf;
        unsigned short* Bt = At + 2048;
        async16(pa + (size_t)t*64, At + tid*8);
        int kt = (t & 15) << 6;
        #pragma unroll
        for(int rd=0; rd<2; rd++) async16(pb[rd] + kt, Bt + rd*2048 + tid*8);
    };
    auto comp = [&](const char* buf){
        const unsigned short* At = (const unsigned short*)buf;
        const unsigned short* Bt = At + 2048;
        #pragma unroll
        for(int kb=0; kb<2; kb++){
            f16x8 af = *(const f16x8*)&At[(wm*16 + l16)*64 + (((kb*4+quad)^sw)<<3)];
            #pragma unroll
            for(int nt2=0; nt2<2; nt2++){
                f16x8 bf = *(const f16x8*)&Bt[(wn*32 + nt2*16 + l16)*64 + (((kb*4+quad)^sw)<<3)];
                pacc[nt2] = mfma16h(af, bf, pacc[nt2]);
            }
        }
    };
    auto fold = [&](int k){
        #pragma unroll
        for(int nt2=0;nt2<2;nt2++){
            float q = (k==0) ? 0.5f : ((k==1) ? q1v[nt2] : q2v[nt2]);
            tot[nt2] += q * pacc[nt2];
            pacc[nt2] = zero;
        }
    };
    char* b0 = smem; char* b1 = smem + 12288; char* b2 = smem + 24576;
    stage(b0,0); stage(b1,1);                   // 6 loads/thread in flight
    wait_vmcnt<3>(); __builtin_amdgcn_s_barrier();
    for(int kk=0; kk<46; kk++){
        stage(b2, kk+2);
        comp(b0);
        if((kk&15)==15) fold(kk>>4);            // t=15 -> phase0, t=31 -> phase1
        wait_vmcnt<3>(); __builtin_amdgcn_s_barrier();
        char* tp=b0; b0=b1; b1=b2; b2=tp;
    }
    comp(b0);                                   // t=46
    wait_vmcnt<0>(); __builtin_amdgcn_s_barrier();
    comp(b1);                                   // t=47
    fold(2);
    __syncthreads();
    // ---- epilogue: write l (hi/lo bf16) to LDS, load W_l, small MFMA, relu, emit ----
    #pragma unroll
    for(int nt2=0; nt2<2; nt2++){
        int h = wn*32 + nt2*16 + l16;
        #pragma unroll
        for(int rr=0; rr<4; rr++){
            int i = wm*16 + quad*4 + rr;
            float v = tot[nt2][rr];
            unsigned short hh = f2b(v);
            Lh[i*SR + h] = hh;
            Ll[i*SR + h] = f2b(v - b2f(hh));
        }
    }
    {
        int k = tid>>2, n0 = (tid&3)*16;
        for(int j=0;j<16;j++){
            float w = Wl1a[k*64 + n0 + j];
            unsigned short hh = f2b(w);
            Wh[(n0+j)*SR + k] = hh;
            Wo[(n0+j)*SR + k] = f2b(w - b2f(hh));
        }
    }
    __syncthreads();
    f32x4 acc[2] = {zero,zero};
    #pragma unroll
    for(int kc=0;kc<2;kc++){
        bf16x8 ah = *(const bf16x8*)&Lh[(wm*16+l16)*SR + kc*32 + quad*8];
        bf16x8 al = *(const bf16x8*)&Ll[(wm*16+l16)*SR + kc*32 + quad*8];
        #pragma unroll
        for(int nt2=0;nt2<2;nt2++){
            bf16x8 bh = *(const bf16x8*)&Wh[(wn*32+nt2*16+l16)*SR + kc*32 + quad*8];
            bf16x8 bl = *(const bf16x8*)&Wo[(wn*32+nt2*16+l16)*SR + kc*32 + quad*8];
            acc[nt2] = mfma16(ah, bh, acc[nt2]);
            acc[nt2] = mfma16(ah, bl, acc[nt2]);
            acc[nt2] = mfma16(al, bh, acc[nt2]);
        }
    }
    int gi = i0 + wm*16 + quad*4;
    float4 xav = *(const float4*)&xa[(b<<10) + gi];
    float xr[4] = {xav.x, xav.y, xav.z, xav.w};
    if(!LAST){
        #pragma unroll
        for(int nt2=0;nt2<2;nt2++){
            int h = wn*32 + nt2*16 + l16;
            float wx = Wx1a[h];
            ushort4 w0;
            #pragma unroll
            for(int rr=0;rr<4;rr++){
                float u = fmaxf(acc[nt2][rr] + xr[rr]*wx, 0.f);
                bool pad = (gi+rr == 1023);
                ((unsigned short*)&w0)[rr] = pad?(unsigned short)0:f2h(u);
            }
            *(ushort4*)&Bnext[(((size_t)(b*64 + h))<<10) + gi] = w0;
        }
    } else {
        #pragma unroll
        for(int nt2=0;nt2<2;nt2++){
            int h = wn*32 + nt2*16 + l16; float wx = Wx1a[h];
            #pragma unroll
            for(int rr=0;rr<4;rr++)
                ua[(((size_t)b<<10)+gi+rr)*64 + h] = fmaxf(acc[nt2][rr] + xr[rr]*wx, 0.f);
        }
        __syncthreads();
        { int k = tid>>2, n0 = (tid&3)*16;
          for(int j=0;j<16;j++){
              float w = Wl1b[k*64 + n0 + j];
              unsigned short hh = f2b(w);
              Wh[(n0+j)*SR + k] = hh;
              Wo[(n0+j)*SR + k] = f2b(w - b2f(hh));
          } }
        __syncthreads();
        f32x4 acc2[2] = {zero,zero};
        #pragma unroll
        for(int kc=0;kc<2;kc++){
            bf16x8 ah = *(const bf16x8*)&Lh[(wm*16+l16)*SR + kc*32 + quad*8];
            bf16x8 al = *(const bf16x8*)&Ll[(wm*16+l16)*SR + kc*32 + quad*8];
            #pragma unroll
            for(int nt2=0;nt2<2;nt2++){
                bf16x8 bh = *(const bf16x8*)&Wh[(wn*32+nt2*16+l16)*SR + kc*32 + quad*8];
                bf16x8 bl = *(const bf16x8*)&Wo[(wn*32+nt2*16+l16)*SR + kc*32 + quad*8];
                acc2[nt2] = mfma16(ah, bh, acc2[nt2]);
                acc2[nt2] = mfma16(ah, bl, acc2[nt2]);
                acc2[nt2] = mfma16(al, bh, acc2[nt2]);
            }
        }
        #pragma unroll
        for(int nt2=0;nt2<2;nt2++){
            int h = wn*32 + nt2*16 + l16; float wx = Wx1b[h];
            #pragma unroll
            for(int rr=0;rr<4;rr++)
                ub[(((size_t)b<<10)+gi+rr)*64 + h] = fmaxf(acc2[nt2][rr] + xr[rr]*wx, 0.f);
        }
    }
}

// ---------------- x2 = concat(ua,ub) @ W_x_2  (hi/lo MFMA, 2 K-phases) -------------------
__global__ __launch_bounds__(256) void x2_k(const float* __restrict__ ua,
        const float* __restrict__ ub, const float* __restrict__ Wx2,
        float* __restrict__ x2){
    int mt = blockIdx.x, b = blockIdx.y;
    int i0 = mt*64;
    int tid = threadIdx.x, wave=tid>>6, lane=tid&63, quad=lane>>4, l16=lane&15;
    __shared__ __align__(16) unsigned short Uh[64*SR], Ul[64*SR];
    __shared__ __align__(16) unsigned short Wh[128*SR], Wo[128*SR];
    f32x4 zero = {0.f,0.f,0.f,0.f};
    f32x4 acc[8];
    #pragma unroll
    for(int nt=0;nt<8;nt++) acc[nt]=zero;
    for(int ph=0; ph<2; ph++){
        if(ph) __syncthreads();
        {
            int k = tid>>2, n0 = (tid&3)*32;
            for(int j=0;j<32;j++){
                float w = Wx2[(ph*64 + k)*128 + n0 + j];
                unsigned short hh = f2b(w);
                Wh[(n0+j)*SR + k] = hh;
                Wo[(n0+j)*SR + k] = f2b(w - b2f(hh));
            }
            int i = tid>>2, c0 = (tid&3)*16;
            const float* src = (ph ? ub : ua) + (((size_t)b<<10)+i0+i)*64 + c0;
            #pragma unroll
            for(int j=0;j<4;j++){
                float4 v = *(const float4*)(src + j*4);
                float vv[4] = {v.x, v.y, v.z, v.w};
                #pragma unroll
                for(int t=0;t<4;t++){
                    unsigned short hh = f2b(vv[t]);
                    Uh[i*SR + c0 + j*4 + t] = hh;
                    Ul[i*SR + c0 + j*4 + t] = f2b(vv[t] - b2f(hh));
                }
            }
        }
        __syncthreads();
        #pragma unroll
        for(int kc=0;kc<2;kc++){
            bf16x8 ah = *(const bf16x8*)&Uh[(wave*16+l16)*SR + kc*32 + quad*8];
            bf16x8 al = *(const bf16x8*)&Ul[(wave*16+l16)*SR + kc*32 + quad*8];
            #pragma unroll
            for(int nt=0;nt<8;nt++){
                bf16x8 bh = *(const bf16x8*)&Wh[(nt*16+l16)*SR + kc*32 + quad*8];
                bf16x8 bl = *(const bf16x8*)&Wo[(nt*16+l16)*SR + kc*32 + quad*8];
                acc[nt] = mfma16(ah, bh, acc[nt]);
                acc[nt] = mfma16(ah, bl, acc[nt]);
                acc[nt] = mfma16(al, bh, acc[nt]);
            }
        }
    }
    int gi = i0 + wave*16 + quad*4;
    #pragma unroll
    for(int nt=0;nt<8;nt++){
        int h = nt*16 + l16;
        #pragma unroll
        for(int rr=0;rr<4;rr++)
            x2[(((size_t)b<<10)+gi+rr)*128 + h] = acc[nt][rr];
    }
}

// ======== fused T2: structured-B GEMM (M=32, N=128) + reduce2 epilogue ===================
// G = gamma^T [b][h][c] fp16 (256 KB/batch, L2-resident); 3 phases x 16 steps; fold by q_k.
// 512 blocks, 2/CU (LDS 60 KB); ring 3 x 20480 B, counted vmcnt(5).
template<bool LAST>
__global__ __launch_bounds__(256) void fused2_k(const unsigned short* __restrict__ Ap,
        const unsigned short* __restrict__ BT,
        const float* __restrict__ Wl2, const float* __restrict__ x2,
        const float* __restrict__ We2, const float* __restrict__ WQ,
        unsigned short* __restrict__ Bnext, float* __restrict__ out){
    int mt, b; decode_swz(blockIdx.x, mt, b);
    int i0 = mt*32;
    int tid = threadIdx.x, wave=tid>>6, lane=tid&63, quad=lane>>4, l16=lane&15;
    int wm = wave>>1, wn = wave&1;
    __shared__ __align__(16) char smem[61440];
    __shared__ float red[4];
    unsigned short* Lh = (unsigned short*)smem;             // 32*SR*2 = 4608
    unsigned short* Ll = (unsigned short*)(smem + 4608);
    unsigned short* Wh = (unsigned short*)(smem + 9216);    // 128*SR*2 = 18432
    unsigned short* Wo = (unsigned short*)(smem + 27648);   // ends 46080

    f32x4 zero = {0.f,0.f,0.f,0.f};
    f32x4 tot[4] = {zero,zero,zero,zero};
    f32x4 pacc[4] = {zero,zero,zero,zero};
    float q1v[4], q2v[4];
    #pragma unroll
    for(int nt=0;nt<4;nt++){
        float we = We2[wn*64 + nt*16 + l16];
        q1v[nt] = C1f*we; q2v[nt] = C3f*we*we*we;
    }
    const unsigned short* pa;
    const unsigned short* pb[4];
    {
        int r = tid>>3, ch = tid&7;
        pa = Ap + ((size_t)(b<<10) + i0 + r)*KTOT + ((ch ^ (r&7))<<3);
    }
    #pragma unroll
    for(int rd=0; rd<4; rd++){
        int idx = rd*256 + tid, r = idx>>3, ch = idx&7;
        pb[rd] = BT + (((size_t)(b*128 + r))<<10) + ((ch ^ (r&7))<<3);
    }
    int sw = l16&7;
    auto stage = [&](char* buf, int t){
        unsigned short* At = (unsigned short*)buf;
        unsigned short* Bt = At + 2048;
        async16(pa + (size_t)t*64, At + tid*8);
        int kt = (t & 15) << 6;
        #pragma unroll
        for(int rd=0; rd<4; rd++) async16(pb[rd] + kt, Bt + rd*2048 + tid*8);
    };
    auto comp = [&](const char* buf){
        const unsigned short* At = (const unsigned short*)buf;
        const unsigned short* Bt = At + 2048;
        #pragma unroll
        for(int kb=0; kb<2; kb++){
            f16x8 af = *(const f16x8*)&At[(wm*16 + l16)*64 + (((kb*4+quad)^sw)<<3)];
            #pragma unroll
            for(int nt=0; nt<4; nt++){
                f16x8 bf = *(const f16x8*)&Bt[(wn*64 + nt*16 + l16)*64 + (((kb*4+quad)^sw)<<3)];
                pacc[nt] = mfma16h(af, bf, pacc[nt]);
            }
        }
    };
    auto fold = [&](int k){
        #pragma unroll
        for(int nt=0;nt<4;nt++){
            float q = (k==0) ? 0.5f : ((k==1) ? q1v[nt] : q2v[nt]);
            tot[nt] += q * pacc[nt];
            pacc[nt] = zero;
        }
    };
    char* b0 = smem; char* b1 = smem + 20480; char* b2 = smem + 40960;
    stage(b0,0); stage(b1,1);                   // 10 loads/thread in flight
    wait_vmcnt<5>(); __builtin_amdgcn_s_barrier();
    for(int kk=0; kk<46; kk++){
        stage(b2, kk+2);
        comp(b0);
        if((kk&15)==15) fold(kk>>4);
        wait_vmcnt<5>(); __builtin_amdgcn_s_barrier();
        char* tp=b0; b0=b1; b1=b2; b2=tp;
    }
    comp(b0);
    wait_vmcnt<0>(); __builtin_amdgcn_s_barrier();
    comp(b1);
    fold(2);
    __syncthreads();
    // ---- epilogue: 2 phases over k-halves; waves with wn==ph own that l-half ----
    f32x4 fac[4] = {zero,zero,zero,zero};
    #pragma unroll
    for(int ph=0; ph<2; ph++){
        if(ph) __syncthreads();
        if(wn == ph){
            #pragma unroll
            for(int nt=0; nt<4; nt++){
                int hh_col = nt*16 + l16;
                #pragma unroll
                for(int rr=0; rr<4; rr++){
                    int i = wm*16 + quad*4 + rr;
                    float v = tot[nt][rr];
                    unsigned short hh = f2b(v);
                    Lh[i*SR + hh_col] = hh;
                    Ll[i*SR + hh_col] = f2b(v - b2f(hh));
                }
            }
        }
        {
            int k = tid>>2, n0 = (tid&3)*32;
            for(int j=0;j<32;j++){
                float w = Wl2[(ph*64 + k)*128 + n0 + j];
                unsigned short hh = f2b(w);
                Wh[(n0+j)*SR + k] = hh;
                Wo[(n0+j)*SR + k] = f2b(w - b2f(hh));
            }
        }
        __syncthreads();
        #pragma unroll
        for(int kc=0;kc<2;kc++){
            bf16x8 ah = *(const bf16x8*)&Lh[(wm*16+l16)*SR + kc*32 + quad*8];
            bf16x8 al = *(const bf16x8*)&Ll[(wm*16+l16)*SR + kc*32 + quad*8];
            #pragma unroll
            for(int nt=0;nt<4;nt++){
                bf16x8 bh = *(const bf16x8*)&Wh[(wn*64+nt*16+l16)*SR + kc*32 + quad*8];
                bf16x8 bl = *(const bf16x8*)&Wo[(wn*64+nt*16+l16)*SR + kc*32 + quad*8];
                fac[nt] = mfma16(ah, bh, fac[nt]);
                fac[nt] = mfma16(ah, bl, fac[nt]);
                fac[nt] = mfma16(al, bh, fac[nt]);
            }
        }
    }
    int gi = i0 + wm*16 + quad*4;
    float qp = 0.f;
    #pragma unroll
    for(int nt=0;nt<4;nt++){
        int h = wn*64 + nt*16 + l16;
        float g[4];
        #pragma unroll
        for(int rr=0;rr<4;rr++)
            g[rr] = fmaxf(fac[nt][rr] + x2[(((size_t)b<<10)+gi+rr)*128 + h], 0.f);
        if(!LAST){
            ushort4 w0;
            #pragma unroll
            for(int rr=0;rr<4;rr++){
                bool pad = (gi+rr == 1023);
                ((unsigned short*)&w0)[rr] = pad?(unsigned short)0:f2h(g[rr]);
            }
            *(ushort4*)&Bnext[(((size_t)(b*128 + h))<<10) + gi] = w0;
        } else {
            float wq = WQ[h];
            #pragma unroll
            for(int rr=0;rr<4;rr++) qp = fmaf(g[rr], wq, qp);
        }
    }
    if(LAST){
        for(int o=32;o>0;o>>=1) qp += __shfl_xor(qp,o,64);
        if(lane==0) red[wave]=qp;
        __syncthreads();
        if(tid==0) atomicAdd(&out[b], red[0]+red[1]+red[2]+red[3]);
    }
}

// ---------------- host launch ------------------------------------------------------------
extern "C" void kernel_launch(void* const* d_in, const int* in_sizes, int n_in,
                              void* d_out, int out_size, void* d_ws, size_t ws_size,
                              hipStream_t stream){
    (void)in_sizes; (void)n_in; (void)out_size; (void)ws_size;
    const float* xs   = (const float*)d_in[0];
    const float* ap   = (const float*)d_in[1];
    const float* act  = (const float*)d_in[2];
    const float* edge = (const float*)d_in[3];
    const float* avail= (const float*)d_in[4];
    const float* ua0  = (const float*)d_in[5];
    const float* g0   = (const float*)d_in[7];
    const float* W1p  = (const float*)d_in[8];
    const float* W2p  = (const float*)d_in[9];
    const float* Wx1a = (const float*)d_in[10];
    const float* We1a = (const float*)d_in[11];
    const float* Wl1a = (const float*)d_in[12];
    const float* Wx1b = (const float*)d_in[13];
    const float* Wl1b = (const float*)d_in[15];
    const float* Wx2  = (const float*)d_in[16];
    const float* We2  = (const float*)d_in[17];
    const float* Wl2  = (const float*)d_in[18];
    const float* WQ   = (const float*)d_in[19];
    float* out = (float*)d_out;

    char* ws = (char*)d_ws;
    // A' (persistent): 16*1024*3072*2 = 100,663,296 B
    unsigned short* Abuf = (unsigned short*)ws;
    char* r2 = ws + 100663296;
    // P/D (fp16) live only until abuild; aliased with G buffers after:
    unsigned short* Pbuf = (unsigned short*)r2;                      // 33,521,664
    unsigned short* Dbuf = (unsigned short*)(r2 + 33521664);         // 33,521,664 (ends 67,043,328)
    unsigned short* BT1a = (unsigned short*)r2;                      //  2,097,152 (G1: 16*64*1024*2)
    unsigned short* BT1b = (unsigned short*)(r2 + 6291456);          //  2,097,152
    unsigned short* BT2a = (unsigned short*)(r2 + 12582912);         //  4,194,304 (G2: 16*128*1024*2)
    unsigned short* BT2b = (unsigned short*)(r2 + 25165824);         //  4,194,304
    float* uaB           = (float*)(r2 + 117440512);                 //  4,194,304
    float* ubB           = (float*)(r2 + 121634816);                 //  4,194,304
    float* x2B           = (float*)(r2 + 125829120);                 //  8,388,608
    float* xaB           = (float*)(r2 + 134217728);                 //     65,536
    unsigned short* BT1[2] = {BT1a, BT1b};
    unsigned short* BT2[2] = {BT2a, BT2b};

    hipMemsetAsync(d_out, 0, BATCH*sizeof(float), stream);
    xa_k<<<64,256,0,stream>>>(xs, ap, act, xaB);
    presence_k<<<dim3(CITIES,BATCH),128,0,stream>>>(edge, W1p, W2p, avail, Pbuf, Dbuf);
    abuild_k<<<dim3(32,32,BATCH),256,0,stream>>>(Pbuf, Dbuf, Abuf);
    binit_k<<<dim3(4,64,BATCH),256,0,stream>>>(ua0, BT1[0], 64);
    for(int it=0; it<5; it++){
        if(it<4)
            fused1_k<false><<<512,256,0,stream>>>(Abuf, BT1[it&1], Wl1a, Wl1b,
                Wx1a, Wx1b, We1a, xaB, BT1[(it+1)&1], uaB, ubB);
        else
            fused1_k<true><<<512,256,0,stream>>>(Abuf, BT1[it&1], Wl1a, Wl1b,
                Wx1a, Wx1b, We1a, xaB, BT1[(it+1)&1], uaB, ubB);
    }
    x2_k<<<dim3(16,BATCH),256,0,stream>>>(uaB, ubB, Wx2, x2B);
    binit_k<<<dim3(4,128,BATCH),256,0,stream>>>(g0, BT2[0], 128);
    for(int it=0; it<5; it++){
        if(it<4)
            fused2_k<false><<<512,256,0,stream>>>(Abuf, BT2[it&1], Wl2, x2B,
                We2, WQ, BT2[(it+1)&1], out);
        else
            fused2_k<true><<<512,256,0,stream>>>(Abuf, BT2[it&1], Wl2, x2B,
                We2, WQ, BT2[(it+1)&1], out);
    }
}